// Round 11
// baseline (79.550 us; speedup 1.0000x reference)
//
#include <hip/hip_runtime.h>
#include <stdint.h>

typedef _Float16 f16x8 __attribute__((ext_vector_type(8)));
typedef float    f32x4 __attribute__((ext_vector_type(4)));

#define H 56
#define W 56
#define C_IN 32
#define N_OUT 64
#define CP 40        // c-dim padded to 40 halves: col stride 80 B (16B-aligned b128,
                     // 20-dword stride -> uniform bank spread on frag reads)
#define NWF 9216     // wf dwords: 9 ij * 4 nt * 64 lane * 4 dw

__device__ __forceinline__ float q16f(float v) { return (float)(_Float16)v; }

// tiny prep: pack weights into MFMA A-fragment order (runs ONCE, 36 blocks).
// dword o = ((ij*4+nt)*64 + lane)*4 + t2:
//   A[m = nt*16 + (lane&15) -> n][k = (lane>>4)*8 + 2*t2 + {0,1} -> c]
__global__ __launch_bounds__(256) void wpack_kernel(
    const float* __restrict__ weight, uint32_t* __restrict__ wf)
{
    int o    = blockIdx.x * 256 + threadIdx.x;    // < 9216
    int t2   = o & 3;
    int lane = (o >> 2) & 63;
    int u    = o >> 8;                            // ij*4 + nt
    int nt   = u & 3, ij = u >> 2;
    int n    = nt * 16 + (lane & 15);
    int c0   = (lane >> 4) * 8 + 2 * t2;
    const float* ws = weight + n * 288 + c0 * 9 + ij;
    _Float16 lo = (_Float16)ws[0];
    _Float16 hi = (_Float16)ws[9];
    wf[o] = (uint32_t)__builtin_bit_cast(uint16_t, lo) |
            ((uint32_t)__builtin_bit_cast(uint16_t, hi) << 16);
}

// conv: in-block x staging (f32->f16, channel-innermost) + 9 shifted K=32 GEMMs.
// wave = 1 oh row x 32 ow (two 16-px B-frag groups share each A-frag) x 64 n.
__global__ __launch_bounds__(256, 3) void conv_mfma(
    const float* __restrict__ x,        // [16,32,56,56]
    const f16x8* __restrict__ wf,       // A-fragment layout (packed once)
    const float* __restrict__ bias,     // [64]
    float* __restrict__ out)            // [16,64,56,56]
{
    __shared__ __align__(16) _Float16 sX[6 * 34 * CP];   // 16,320 B: [r][col][c]

    const int tid = threadIdx.x;
    const int b   = blockIdx.z;
    const int oh0 = blockIdx.y * 4;
    const int bx  = blockIdx.x;
    const int ow0 = bx * 24;            // tiles cover ow 0-31 and 24-55 (overlap masked)

    // ---- stage x window: c 0..31, r 0..5 (ih=oh0+r-1), col 0..33 (iw=ow0+col-1)
    // col is the fast index -> coalesced global runs of 34 dwords.
    #pragma unroll
    for (int k = 0; k < 26; ++k) {
        int f = k * 256 + tid;
        if (f < 6528) {
            int col = f % 34;
            int u   = f / 34;           // c*6 + r
            int r   = u % 6;
            int c   = u / 6;
            int ih = oh0 + r - 1, iw = ow0 + col - 1;
            float v = 0.f;
            if ((unsigned)ih < (unsigned)H && (unsigned)iw < (unsigned)W)
                v = x[((b * C_IN + c) * H + ih) * W + iw];
            sX[(r * 34 + col) * CP + c] = (_Float16)v;
        }
    }
    __syncthreads();

    const int wid  = tid >> 6;          // oh row 0..3
    const int lane = tid & 63;
    const int quad = lane >> 4;
    const int px   = lane & 15;
    const int oh   = oh0 + wid;

    f32x4 acc[2][4] = {{{0,0,0,0},{0,0,0,0},{0,0,0,0},{0,0,0,0}},
                       {{0,0,0,0},{0,0,0,0},{0,0,0,0},{0,0,0,0}}};

    #pragma unroll
    for (int ij = 0; ij < 9; ++ij) {
        const int i = ij / 3, jj = ij - 3 * i;
        // B[k=c][n=px]: 16 contiguous bytes, 16B-aligned (col stride 80 B)
        const _Float16* xb = &sX[((wid + i) * 34 + px + jj) * CP + quad * 8];
        f16x8 xf0 = *(const f16x8*)xb;                  // ds_read_b128
        f16x8 xf1 = *(const f16x8*)(xb + 16 * CP);
        #pragma unroll
        for (int nt = 0; nt < 4; ++nt) {
            f16x8 wv = wf[(ij * 4 + nt) * 64 + lane];   // global dwordx4, L1/L2-hot
            acc[0][nt] = __builtin_amdgcn_mfma_f32_16x16x32_f16(wv, xf0, acc[0][nt], 0, 0, 0);
            acc[1][nt] = __builtin_amdgcn_mfma_f32_16x16x32_f16(wv, xf1, acc[1][nt], 0, 0, 0);
        }
    }

    // ---- epilogue: out = q16(acc + q16(bias)); quarter-wave = one full 64B line.
    // overlap columns 24..31 owned by tile bx==0.
    #pragma unroll
    for (int xg = 0; xg < 2; ++xg) {
        const int ow = ow0 + 16 * xg + px;
        if (bx == 0 || ow >= 32) {
            #pragma unroll
            for (int nt = 0; nt < 4; ++nt) {
                #pragma unroll
                for (int reg = 0; reg < 4; ++reg) {
                    const int n = nt * 16 + quad * 4 + reg;
                    out[((size_t)(b * N_OUT + n) * H + oh) * W + ow] =
                        q16f(acc[xg][nt][reg] + q16f(bias[n]));
                }
            }
        }
    }
}

extern "C" void kernel_launch(void* const* d_in, const int* in_sizes, int n_in,
                              void* d_out, int out_size, void* d_ws, size_t ws_size,
                              hipStream_t stream) {
    const float* x      = (const float*)d_in[0];
    const float* weight = (const float*)d_in[1];
    const float* bias   = (const float*)d_in[2];
    float* out          = (float*)d_out;
    uint32_t* wfp       = (uint32_t*)d_ws;        // 36,864 B

    wpack_kernel<<<dim3(NWF / 256), dim3(256), 0, stream>>>(weight, wfp);
    conv_mfma<<<dim3(2, 14, 16), dim3(256), 0, stream>>>(x, (const f16x8*)wfp, bias, out);
}

// Round 12
// 71.588 us; speedup vs baseline: 1.1112x; 1.1112x over previous
//
#include <hip/hip_runtime.h>
#include <stdint.h>

typedef _Float16 f16x8 __attribute__((ext_vector_type(8)));
typedef float    f32x4 __attribute__((ext_vector_type(4)));

#define H 56
#define W 56
#define C_IN 32
#define N_OUT 64
#define PR 58                 // padded rows, row = ih+1
#define PCOLS 58              // padded cols, col = iw+1 (0 and 57 are the zero pads)
#define XB_BLOCKS (16 * PR)   // 928 transpose blocks
#define NWF 9216              // wf dwords: 9 ij * 4 nt * 64 lane * 4 dw
#define XPAD_BYTES ((size_t)16 * PR * PCOLS * C_IN * 2)   // 3,444,736 B (256-aligned)

__device__ __forceinline__ float q16f(float v) { return (float)(_Float16)v; }

// merged prep: blocks [0,928) transpose x to channel-innermost f16 with zero
// padding; blocks [928,964) pack weights into MFMA A-fragment order.
__global__ __launch_bounds__(256) void prep_kernel(
    const float* __restrict__ x, const float* __restrict__ weight,
    _Float16* __restrict__ xpad, uint32_t* __restrict__ wf)
{
    const int nb  = blockIdx.x;
    const int tid = threadIdx.x;
    if (nb < XB_BLOCKS) {
        // one block = one (b,row): x[b][c][ih][iw] -> xpad[b][row][col][c]
        __shared__ _Float16 sT[PCOLS * 34];   // col stride 34 f16 (17 dw) kills conflicts
        const int b = nb / PR, row = nb % PR, ih = row - 1;
        const bool interior = (unsigned)ih < (unsigned)H;
        if (interior) {
            // zero only the two pad columns (cols 1..56 are fully overwritten)
            if (tid < 32) {
                int col = (tid >> 4) * 57, cd = tid & 15;
                ((uint32_t*)sT)[col * 17 + cd] = 0u;
            }
            __syncthreads();
            #pragma unroll
            for (int k = 0; k < 7; ++k) {       // 7*256 = 1792 = 32c * 56iw
                int idx = k * 256 + tid;
                int c = idx / W, iw = idx - c * W;
                sT[(iw + 1) * 34 + c] = (_Float16)x[((b * C_IN + c) * H + ih) * W + iw];
            }
        } else {
            // halo row: everything zero
            for (int i = tid; i < PCOLS * 17; i += 256) ((uint32_t*)sT)[i] = 0u;
        }
        __syncthreads();
        // write out 928 dwords as 464 coalesced uint2
        uint2* dst = (uint2*)(xpad + ((size_t)b * PR + row) * PCOLS * C_IN);
        for (int i = tid; i < PCOLS * 8; i += 256) {
            int col = i >> 3, cd2 = i & 7;
            const uint32_t* s = &((const uint32_t*)sT)[col * 17 + 2 * cd2];
            uint2 v = { s[0], s[1] };
            dst[i] = v;
        }
    } else {
        // A-frag pack: dword o = ((ij*4+nt)*64 + lane)*4 + t2
        // A[m = nt*16 + (lane&15) -> n][k = (lane>>4)*8 + 2*t2 + {0,1} -> c]
        int o = (nb - XB_BLOCKS) * 256 + tid;           // < 9216
        int t2   = o & 3;
        int lane = (o >> 2) & 63;
        int u    = o >> 8;
        int nt   = u & 3, ij = u >> 2;
        int n    = nt * 16 + (lane & 15);
        int c0   = (lane >> 4) * 8 + 2 * t2;
        _Float16 lo = (_Float16)weight[n * 288 + c0 * 9 + ij];
        _Float16 hi = (_Float16)weight[n * 288 + (c0 + 1) * 9 + ij];
        wf[o] = (uint32_t)__builtin_bit_cast(uint16_t, lo) |
                ((uint32_t)__builtin_bit_cast(uint16_t, hi) << 16);
    }
}

// conv as 9 shifted K=32 GEMMs, no LDS, no barrier.
// wave = 1 oh row x 32 ow (two 16-px B-frag groups sharing A) x 64 n.
__global__ __launch_bounds__(256, 2) void conv_mfma(
    const _Float16* __restrict__ xpad,   // [16][58][58][32] f16
    const f16x8*    __restrict__ wf,     // A-fragment layout
    const float*    __restrict__ bias,   // [64]
    float* __restrict__ out)             // [16,64,56,56]
{
    const int tid  = threadIdx.x;
    const int b    = blockIdx.z;
    const int oh   = blockIdx.y * 4 + (tid >> 6);
    const int bx   = blockIdx.x;
    const int ow0  = bx * 24;            // tiles cover ow 0-31 and 24-55
    const int lane = tid & 63;
    const int quad = lane >> 4;
    const int px   = lane & 15;

    // B-frag bases: B[k=c][n=px], k = quad*8+t -> 16 contiguous bytes per load
    const _Float16* xb0 = xpad + (((size_t)b * PR + oh) * PCOLS + ow0 + px) * C_IN + quad * 8;
    const _Float16* xb1 = xb0 + 16 * C_IN;

    f32x4 acc[2][4] = {{{0,0,0,0},{0,0,0,0},{0,0,0,0},{0,0,0,0}},
                       {{0,0,0,0},{0,0,0,0},{0,0,0,0},{0,0,0,0}}};

    #pragma unroll
    for (int ij = 0; ij < 9; ++ij) {
        const int i = ij / 3, jj = ij - 3 * i;
        const int sh = (i * PCOLS + jj) * C_IN;
        f16x8 xf0 = *(const f16x8*)(xb0 + sh);              // dwordx4, L1/L2-hot
        f16x8 xf1 = *(const f16x8*)(xb1 + sh);
        #pragma unroll
        for (int nt = 0; nt < 4; ++nt) {
            f16x8 wv = wf[(ij * 4 + nt) * 64 + lane];       // dwordx4, L1/L2-hot
            acc[0][nt] = __builtin_amdgcn_mfma_f32_16x16x32_f16(wv, xf0, acc[0][nt], 0, 0, 0);
            acc[1][nt] = __builtin_amdgcn_mfma_f32_16x16x32_f16(wv, xf1, acc[1][nt], 0, 0, 0);
        }
    }

    // epilogue: out = q16(acc + q16(bias)); quarter-wave = one full 64B line.
    // overlap columns 24..31 are owned by tile bx==0.
    #pragma unroll
    for (int xg = 0; xg < 2; ++xg) {
        const int ow = ow0 + 16 * xg + px;
        if (bx == 0 || ow >= 32) {
            #pragma unroll
            for (int nt = 0; nt < 4; ++nt) {
                #pragma unroll
                for (int reg = 0; reg < 4; ++reg) {
                    const int n = nt * 16 + quad * 4 + reg;
                    out[((size_t)(b * N_OUT + n) * H + oh) * W + ow] =
                        q16f(acc[xg][nt][reg] + q16f(bias[n]));
                }
            }
        }
    }
}

extern "C" void kernel_launch(void* const* d_in, const int* in_sizes, int n_in,
                              void* d_out, int out_size, void* d_ws, size_t ws_size,
                              hipStream_t stream) {
    const float* x      = (const float*)d_in[0];
    const float* weight = (const float*)d_in[1];
    const float* bias   = (const float*)d_in[2];
    float* out          = (float*)d_out;

    _Float16* xpad = (_Float16*)d_ws;
    uint32_t* wfp  = (uint32_t*)((char*)d_ws + XPAD_BYTES);   // 36,864 B

    prep_kernel<<<dim3(XB_BLOCKS + NWF / 256), dim3(256), 0, stream>>>(x, weight, xpad, wfp);
    conv_mfma<<<dim3(2, 14, 16), dim3(256), 0, stream>>>(xpad, (const f16x8*)wfp, bias, out);
}